// Round 13
// baseline (301.979 us; speedup 1.0000x reference)
//
#include <hip/hip_runtime.h>
#include <hip/hip_bf16.h>
#include <math.h>

#define DIM 1024
#define HID 2048
#define NEXP 8
#define NTOK 1024   // B*T
#define TOPK 2
#define NSLOT (NTOK * TOPK)

typedef __attribute__((ext_vector_type(4))) float f32x4;
typedef __attribute__((ext_vector_type(8))) short bf16x8;
typedef __attribute__((ext_vector_type(4))) short bf16x4;

__device__ inline short bf1(float f) {
    union { __hip_bfloat16 b; short s; } u; u.b = __float2bfloat16(f); return u.s;
}
__device__ inline bf16x4 cvt4(f32x4 v) {
    bf16x4 r;
#pragma unroll
    for (int i = 0; i < 4; ++i) r[i] = bf1(v[i]);
    return r;
}
__device__ inline bf16x8 cat8(bf16x4 lo, bf16x4 hi) {
    bf16x8 r;
#pragma unroll
    for (int i = 0; i < 4; ++i) { r[i] = lo[i]; r[i + 4] = hi[i]; }
    return r;
}

// ---------------- router (fused with x->bf16 convert; also writes per-slot weight) ----------------
__global__ __launch_bounds__(64) void router_kernel(
    const float* __restrict__ x, const float* __restrict__ rw,
    __hip_bfloat16* __restrict__ xb,
    int* __restrict__ counts, int* __restrict__ slot_list, float* __restrict__ w_slot)
{
    int t = blockIdx.x;
    int lane = threadIdx.x;
    const float* xr = x + (size_t)t * DIM;
    f32x4 xv[4];
#pragma unroll
    for (int qq = 0; qq < 4; ++qq) xv[qq] = *(const f32x4*)(xr + qq * 256 + lane * 4);
#pragma unroll
    for (int qq = 0; qq < 4; ++qq)
        *(bf16x4*)(xb + (size_t)t * DIM + qq * 256 + lane * 4) = cvt4(xv[qq]);

    float acc[NEXP];
#pragma unroll
    for (int e = 0; e < NEXP; ++e) {
        const float* rwe = rw + e * DIM;
        f32x4 s4 = (f32x4)(0.f);
#pragma unroll
        for (int qq = 0; qq < 4; ++qq) {
            f32x4 wv = *(const f32x4*)(rwe + qq * 256 + lane * 4);
            s4 += xv[qq] * wv;
        }
        acc[e] = s4[0] + s4[1] + s4[2] + s4[3];
    }
#pragma unroll
    for (int off = 32; off > 0; off >>= 1) {
#pragma unroll
        for (int e = 0; e < NEXP; ++e) acc[e] += __shfl_down(acc[e], off, 64);
    }
    if (lane == 0) {
        int i1 = 0;
#pragma unroll
        for (int e = 1; e < NEXP; ++e) if (acc[e] > acc[i1]) i1 = e;
        int i2 = -1;
#pragma unroll
        for (int e = 0; e < NEXP; ++e) {
            if (e == i1) continue;
            if (i2 < 0 || acc[e] > acc[i2]) i2 = e;
        }
        float w1 = 1.f / (1.f + expf(acc[i2] - acc[i1]));   // softmax renorm over top-2
        float w2 = 1.f - w1;
        int p1 = atomicAdd(&counts[i1], 1);
        slot_list[i1 * NTOK + p1] = t * 2 + 0;
        w_slot[t * 2 + 0] = w1;
        int p2 = atomicAdd(&counts[i2], 1);
        slot_list[i2 * NTOK + p2] = t * 2 + 1;
        w_slot[t * 2 + 1] = w2;
    }
}

#define ADEPTH 8

// ---------------- gate/up partial GEMM: wave-autonomous, zero LDS, zero barriers ----------------
// 1 wave = 1 unit = (expert, 16-col strip, G-or-U). B (16 rows x K=1024) staged
// ONCE into 128 bf16 VGPRs (contiguous f32 row streams, 16 loads in flight),
// then m-loop streams gathered A frags (xb, L2-resident) with 8-kc rolling
// prefetch. 8 independent waves/CU -> no coupled stalls (the wcvt regime).
__global__ __launch_bounds__(256) void gu_partial(
    const __hip_bfloat16* __restrict__ xb, const float* __restrict__ wg,
    const float* __restrict__ wu, const int* __restrict__ counts,
    const int* __restrict__ slot_list, const __hip_bfloat16* __restrict__ zrow,
    float* __restrict__ g_buf, float* __restrict__ u_buf)
{
    int uid = blockIdx.x * 4 + (threadIdx.x >> 6);   // 0..2047
    int tu = uid & 1;                                // 0=G, 1=U
    int es = uid >> 1;                               // 0..1023
    int e = es >> 7;
    int hb = (es & 127) * 16;

    int n_e = counts[e];
    if (n_e == 0) return;                            // no barriers in kernel -> legal per-wave exit
    const int* sl = slot_list + e * NTOK;

    int lane = threadIdx.x & 63;
    int fr = lane & 15, fq = lane >> 4;

    // stage B fragments: lane (fr,fq) holds W[hb+fr][kc*32+fq*8 .. +8] for kc=0..31
    const float* W = (tu ? wu : wg) + (size_t)e * HID * DIM + (size_t)(hb + fr) * DIM + fq * 8;
    bf16x8 B[32];
#pragma unroll
    for (int r = 0; r < 4; ++r) {
        f32x4 lo[8], hi[8];
#pragma unroll
        for (int i = 0; i < 8; ++i) {
            lo[i] = *(const f32x4*)(W + (r * 8 + i) * 32);
            hi[i] = *(const f32x4*)(W + (r * 8 + i) * 32 + 4);
        }
#pragma unroll
        for (int i = 0; i < 8; ++i) B[r * 8 + i] = cat8(cvt4(lo[i]), cvt4(hi[i]));
    }

    float* obuf = tu ? u_buf : g_buf;

#pragma unroll 1
    for (int m0 = 0; m0 < n_e; m0 += 32) {
        int rows = n_e - m0; if (rows > 32) rows = 32;
        const __hip_bfloat16* pA[2];
#pragma unroll
        for (int rg = 0; rg < 2; ++rg) {
            int lr = rg * 16 + fr;
            pA[rg] = ((lr < rows) ? xb + (size_t)(sl[m0 + lr] >> 1) * DIM : zrow) + fq * 8;
        }
        f32x4 acc[2]; acc[0] = (f32x4)(0.f); acc[1] = (f32x4)(0.f);

        bf16x8 a[ADEPTH][2];
#pragma unroll
        for (int k = 0; k < ADEPTH; ++k) {
            a[k][0] = *(const bf16x8*)(pA[0] + k * 32);
            a[k][1] = *(const bf16x8*)(pA[1] + k * 32);
        }
#pragma unroll
        for (int kc = 0; kc < 32; ++kc) {
            bf16x8 a0 = a[kc % ADEPTH][0], a1 = a[kc % ADEPTH][1];
            if (kc + ADEPTH < 32) {
                a[kc % ADEPTH][0] = *(const bf16x8*)(pA[0] + (kc + ADEPTH) * 32);
                a[kc % ADEPTH][1] = *(const bf16x8*)(pA[1] + (kc + ADEPTH) * 32);
            }
            acc[0] = __builtin_amdgcn_mfma_f32_16x16x32_bf16(a0, B[kc], acc[0], 0, 0, 0);
            acc[1] = __builtin_amdgcn_mfma_f32_16x16x32_bf16(a1, B[kc], acc[1], 0, 0, 0);
        }

        // D: row = rg*16 + fq*4 + reg (token order), col = fr -> f32 partials by slot
#pragma unroll
        for (int rg = 0; rg < 2; ++rg)
#pragma unroll
            for (int reg = 0; reg < 4; ++reg) {
                int lr = rg * 16 + fq * 4 + reg;
                if (lr < rows)
                    obuf[(size_t)sl[m0 + lr] * HID + hb + fr] = acc[rg][reg];
            }
    }
}

// ---------------- hcomb: h = w_slot * silu(g) * u -> bf16 (grid-stride dense pass) ----------------
__global__ __launch_bounds__(256) void hcomb_kernel(
    const float* __restrict__ g_buf, const float* __restrict__ u_buf,
    const float* __restrict__ w_slot, __hip_bfloat16* __restrict__ h_buf)
{
    int i = blockIdx.x * 256 + threadIdx.x;          // over NSLOT*HID/4 = 1M
    int slot = i >> 9;                               // HID/4 = 512 chunks per slot
    f32x4 g = *(const f32x4*)(g_buf + (size_t)i * 4);
    f32x4 u = *(const f32x4*)(u_buf + (size_t)i * 4);
    float w = w_slot[slot];
    f32x4 h;
#pragma unroll
    for (int j = 0; j < 4; ++j)
        h[j] = w * (g[j] / (1.f + expf(-g[j]))) * u[j];
    *(bf16x4*)(h_buf + (size_t)i * 4) = cvt4(h);
}

// ---------------- down partial GEMM: wave-autonomous, K split in halves ----------------
// 1 wave = (expert, 16 d-cols, k-half). B (16 rows x 1024) in 128 bf16 VGPRs.
__global__ __launch_bounds__(256) void down_partial(
    const __hip_bfloat16* __restrict__ h_buf, const float* __restrict__ wd,
    const int* __restrict__ counts, const int* __restrict__ slot_list,
    const __hip_bfloat16* __restrict__ zrow, float* __restrict__ ypart)
{
    int uid = blockIdx.x * 4 + (threadIdx.x >> 6);   // 0..1023
    int kh = uid & 1;
    int es = uid >> 1;                               // 0..511
    int e = es >> 6;
    int db = (es & 63) * 16;

    int n_e = counts[e];
    if (n_e == 0) return;
    const int* sl = slot_list + e * NTOK;

    int lane = threadIdx.x & 63;
    int fr = lane & 15, fq = lane >> 4;

    const float* W = wd + (size_t)e * DIM * HID + (size_t)(db + fr) * HID + kh * 1024 + fq * 8;
    bf16x8 B[32];
#pragma unroll
    for (int r = 0; r < 4; ++r) {
        f32x4 lo[8], hi[8];
#pragma unroll
        for (int i = 0; i < 8; ++i) {
            lo[i] = *(const f32x4*)(W + (r * 8 + i) * 32);
            hi[i] = *(const f32x4*)(W + (r * 8 + i) * 32 + 4);
        }
#pragma unroll
        for (int i = 0; i < 8; ++i) B[r * 8 + i] = cat8(cvt4(lo[i]), cvt4(hi[i]));
    }

    float* obuf = ypart + (size_t)kh * NSLOT * DIM;

#pragma unroll 1
    for (int m0 = 0; m0 < n_e; m0 += 32) {
        int rows = n_e - m0; if (rows > 32) rows = 32;
        const __hip_bfloat16* pA[2];
#pragma unroll
        for (int rg = 0; rg < 2; ++rg) {
            int lr = rg * 16 + fr;
            pA[rg] = ((lr < rows) ? h_buf + (size_t)sl[m0 + lr] * HID + kh * 1024 : zrow) + fq * 8;
        }
        f32x4 acc[2]; acc[0] = (f32x4)(0.f); acc[1] = (f32x4)(0.f);

        bf16x8 a[ADEPTH][2];
#pragma unroll
        for (int k = 0; k < ADEPTH; ++k) {
            a[k][0] = *(const bf16x8*)(pA[0] + k * 32);
            a[k][1] = *(const bf16x8*)(pA[1] + k * 32);
        }
#pragma unroll
        for (int kc = 0; kc < 32; ++kc) {
            bf16x8 a0 = a[kc % ADEPTH][0], a1 = a[kc % ADEPTH][1];
            if (kc + ADEPTH < 32) {
                a[kc % ADEPTH][0] = *(const bf16x8*)(pA[0] + (kc + ADEPTH) * 32);
                a[kc % ADEPTH][1] = *(const bf16x8*)(pA[1] + (kc + ADEPTH) * 32);
            }
            acc[0] = __builtin_amdgcn_mfma_f32_16x16x32_bf16(a0, B[kc], acc[0], 0, 0, 0);
            acc[1] = __builtin_amdgcn_mfma_f32_16x16x32_bf16(a1, B[kc], acc[1], 0, 0, 0);
        }

#pragma unroll
        for (int rg = 0; rg < 2; ++rg)
#pragma unroll
            for (int reg = 0; reg < 4; ++reg) {
                int lr = rg * 16 + fq * 4 + reg;
                if (lr < rows)
                    obuf[(size_t)sl[m0 + lr] * DIM + db + fr] = acc[rg][reg];
            }
    }
}

// ---------------- combine: out[t] = sum of both slots' both k-halves ----------------
__global__ __launch_bounds__(256) void combine_kernel(const float* __restrict__ ypart, float* __restrict__ out)
{
    int i = blockIdx.x * 256 + threadIdx.x;          // over NTOK*DIM/4
    int t = i >> 8;
    int c = i & 255;
    const float* y0 = ypart;
    const float* y1 = ypart + (size_t)NSLOT * DIM;
    f32x4 a = ((const f32x4*)(y0 + (size_t)(2 * t) * DIM))[c];
    f32x4 b = ((const f32x4*)(y0 + (size_t)(2 * t + 1) * DIM))[c];
    f32x4 cc = ((const f32x4*)(y1 + (size_t)(2 * t) * DIM))[c];
    f32x4 d = ((const f32x4*)(y1 + (size_t)(2 * t + 1) * DIM))[c];
    f32x4 r = a + b + cc + d;
    ((f32x4*)(out + (size_t)t * DIM))[c] = r;
}

extern "C" void kernel_launch(void* const* d_in, const int* in_sizes, int n_in,
                              void* d_out, int out_size, void* d_ws, size_t ws_size,
                              hipStream_t stream) {
    const float* x  = (const float*)d_in[0];
    const float* rw = (const float*)d_in[1];
    const float* wg = (const float*)d_in[2];
    const float* wu = (const float*)d_in[3];
    const float* wd = (const float*)d_in[4];
    float* out = (float*)d_out;

    char* ws = (char*)d_ws;
    int* counts            = (int*)ws;                                       // 256 B
    int* slot_list         = (int*)(ws + 256);                               // 32 KB
    float* w_slot          = (float*)(ws + 256 + NEXP * NTOK * 4);           // 8 KB
    __hip_bfloat16* xb     = (__hip_bfloat16*)(ws + 256 + NEXP * NTOK * 4 + NSLOT * 4);  // 2 MB
    char* p = (char*)xb + (size_t)NTOK * DIM * 2;
    float* g_buf           = (float*)p;                   p += (size_t)NSLOT * HID * 4;  // 16 MB
    float* u_buf           = (float*)p;                   p += (size_t)NSLOT * HID * 4;  // 16 MB
    __hip_bfloat16* h_buf  = (__hip_bfloat16*)p;          p += (size_t)NSLOT * HID * 2;  // 8 MB
    float* ypart           = (float*)p;                   p += (size_t)2 * NSLOT * DIM * 4; // 16 MB
    __hip_bfloat16* zrow   = (__hip_bfloat16*)p;                                         // 4 KB zeros

    hipMemsetAsync(counts, 0, NEXP * sizeof(int), stream);
    hipMemsetAsync(zrow, 0, HID * sizeof(__hip_bfloat16), stream);
    router_kernel<<<NTOK, 64, 0, stream>>>(x, rw, xb, counts, slot_list, w_slot);
    gu_partial<<<512, 256, 0, stream>>>(xb, wg, wu, counts, slot_list, zrow, g_buf, u_buf);
    hcomb_kernel<<<NSLOT * HID / 4 / 256, 256, 0, stream>>>(g_buf, u_buf, w_slot, h_buf);
    down_partial<<<256, 256, 0, stream>>>(h_buf, wd, counts, slot_list, zrow, ypart);
    combine_kernel<<<NTOK * DIM / 4 / 256, 256, 0, stream>>>(ypart, out);
}